// Round 1
// baseline (157.427 us; speedup 1.0000x reference)
//
#include <hip/hip_runtime.h>
#include <math.h>

#define BB 32
#define CCH 224
#define TTT 2048
#define TPB 64             // t per tile in kf
#define NT  (TTT/TPB)      // 32 tiles
#define CG  14             // chains (channels) per kf block  (was 28)
#define NCG (CCH/CG)       // 16 -> 512 blocks -> 2 blocks/CU
#define ROWS 26            // CG + 12 halo rows
#define XROW 68            // floats per xs row (64 + 4 pad, 16B-aligned)
#define IROW 15            // f64 per I row (14 + 1 pad)

// ---------------------------------------------------------------------------
// kw: per (b,t): f64 dot over C -> w -> 7 symmetric Gaussian taps (f64).
// v2: block = 64 t x 4 channel-quarters (256 thr), LDS reduce. grid (32,32)
// = 1024 blocks = 4 blocks/CU = 16 waves/CU (was 4) -> latency actually hidden.
// Summation order preserved exactly: p_q sequential over its 56 channels,
// combined as (p0+p1)+(p2+p3).
// ---------------------------------------------------------------------------
__global__ __launch_bounds__(256) void kw(
    const float* __restrict__ x, const float* __restrict__ lw,
    double* __restrict__ kernG)
{
    __shared__ double sp[4][64];
    const int b  = blockIdx.y;
    const int tl = threadIdx.x & 63;
    const int q  = threadIdx.x >> 6;           // channel quarter 0..3
    const int t  = blockIdx.x * 64 + tl;

    const float* xb  = x + (((size_t)(b * CCH + 56 * q)) << 11) + t;
    const float* lwq = lw + 56 * q;

    double p = 0.0;
    #pragma unroll 8
    for (int i = 0; i < 56; ++i)
        p += (double)xb[(size_t)i << 11] * (double)lwq[i];
    sp[q][tl] = p;
    __syncthreads();

    if (threadIdx.x < 64) {
        double acc = (sp[0][tl] + sp[1][tl]) + (sp[2][tl] + sp[3][tl]);

        double w = 5.2 + acc * 9.6;
        w = fmin(fmax(w, 0.4), 10.0);
        double iw2 = 1.0 / (w * w);

        // norm over linspace(-60,60,130): exactly symmetric -> 2x half-sum,
        // terms G^{(2u+1)^2} via power recurrence (2 exps total)
        const double s = 120.0 / 129.0;
        double G  = exp(-0.125 * s * s * iw2);
        double G2 = G * G, G4 = G2 * G2, G8 = G4 * G4;
        double term = G, cmul = G8, norm = G;
        for (int u = 1; u <= 64; ++u) { term *= cmul; cmul *= G8; norm += term; }
        norm *= 2.0;

        double P = exp(-0.5 * iw2), P2 = P * P;
        double a = 1.0, bm = P, inv = 1.0 / norm;
        double* kr = kernG + (size_t)(b * TTT + t) * 7;
        kr[0] = inv;                      // center tap
        #pragma unroll
        for (int d = 1; d <= 6; ++d) {
            a *= bm; bm *= P2;
            kr[d] = a * inv;              // tap at distance d (symmetric)
        }
    }
}

// ---------------------------------------------------------------------------
// kf: fused conv + LIF scan + spike output. grid (16, 32) x 192 threads.
// wave0 = scan (14 chains); waves 1-2 = conv/stage/out-write (7 ch each).
// 2 blocks/CU (LDS 36.9 KB/block): sibling block fills dependency holes.
// Pipeline (1 barrier per phase), slot-by-slot identical to v1:
//   phase k: conv(k)->Is[k&1]; stage(k+1)->xs/kd[(k+1)&1]; scan(k-1) reads
//   Is[(k-1)&1] -> bitsb[(k-1)&1]; out-write(k-2) reads bitsb[k&1].
// ---------------------------------------------------------------------------
__global__ __launch_bounds__(192) void kf(
    const float* __restrict__ x, const double* __restrict__ kernG,
    float* __restrict__ out)
{
    __shared__ __align__(16) float xs[2][ROWS][XROW];      // 14144 B
    __shared__ double kd[2][TPB][7];                       //  7168 B
    __shared__ double Is[2][TPB][IROW];                    // 15360 B
    __shared__ unsigned long long bitsb[2][CG];            //   224 B

    const int b   = blockIdx.y;
    const int cgi = blockIdx.x;
    const int c0  = cgi * CG;
    const int tid = threadIdx.x;
    const int ctid = tid - 64;

    const float*  xbase = x + (((size_t)(b * CCH)) << 11);
    const double* kbase = kernG + (size_t)(b * TTT) * 7;
    float* obase = out + (((size_t)(b * CCH + c0)) << 11);

    double mem = 0.0;   // scan state (wave0 lanes)
    bool   r   = false;

    // ---- prologue: stage tile 0 ----
    if (tid >= 64) {
        #pragma unroll
        for (int i2 = 0; i2 < 4; ++i2) {
            int e = ctid + i2 * 128;
            if (e < ROWS * 16) {
                int rr = e >> 4, qq = e & 15;
                int cr = c0 - 6 + rr;
                float4 v = make_float4(0.f, 0.f, 0.f, 0.f);
                if (cr >= 0 && cr < CCH)
                    v = *(const float4*)(xbase + ((size_t)cr << 11) + 4 * qq);
                *(float4*)&xs[0][rr][4 * qq] = v;
            }
        }
        if (ctid < TPB) {
            const double* kp = kbase + (size_t)ctid * 7;
            #pragma unroll
            for (int i2 = 0; i2 < 7; ++i2) kd[0][ctid][i2] = kp[i2];
        }
    }
    __syncthreads();

    for (int k = 0; k <= NT + 1; ++k) {
        if (tid >= 64) {
            const int buf = k & 1, nbuf = (k + 1) & 1;
            // 1) issue global loads for tile k+1 (latency hidden under conv)
            float4 rv[4]; double kv[7];
            const bool st = (k + 1 <= NT - 1);
            if (st) {
                const int gt0 = (k + 1) * TPB;
                #pragma unroll
                for (int i2 = 0; i2 < 4; ++i2) {
                    int e = ctid + i2 * 128;
                    if (e < ROWS * 16) {
                        int rr = e >> 4, qq = e & 15;
                        int cr = c0 - 6 + rr;
                        rv[i2] = make_float4(0.f, 0.f, 0.f, 0.f);
                        if (cr >= 0 && cr < CCH)
                            rv[i2] = *(const float4*)(xbase + ((size_t)cr << 11) + gt0 + 4 * qq);
                    }
                }
                if (ctid < TPB) {
                    const double* kp = kbase + (size_t)(gt0 + ctid) * 7;
                    #pragma unroll
                    for (int i2 = 0; i2 < 7; ++i2) kv[i2] = kp[i2];
                }
            }
            // 2) conv(k): thread = (t, half) -> 7 channels, sliding 13-row ring
            if (k <= NT - 1) {
                const int t  = ctid & 63;
                const int ch = ctid >> 6;       // 0/1
                const int cb = 7 * ch;
                double kk7[7];
                #pragma unroll
                for (int i2 = 0; i2 < 7; ++i2) kk7[i2] = kd[buf][t][i2];
                float xv[13];
                #pragma unroll
                for (int i2 = 0; i2 < 13; ++i2) xv[i2] = xs[buf][cb + i2][t];
                #pragma unroll
                for (int c = 0; c < 7; ++c) {
                    double acc = 0.0;
                    #pragma unroll
                    for (int kk2 = 0; kk2 < 13; ++kk2) {
                        int d = kk2 < 6 ? 6 - kk2 : kk2 - 6;
                        acc = fma((double)xv[(c + kk2) % 13], kk7[d], acc);
                    }
                    double xvv = (double)xv[(c + 6) % 13];
                    double dd  = xvv - acc;
                    Is[buf][t][cb + c] = xvv - (dd > 0.0 ? dd : 0.0);
                    if (c < 6) xv[c % 13] = xs[buf][cb + c + 13][t];
                }
            }
            // 3) out-write(k-2): coalesced float4 spike stores
            if (k >= 2) {
                const int j = k - 2, jb = j & 1;
                const int t0o = j * TPB;
                #pragma unroll
                for (int i2 = 0; i2 < 2; ++i2) {
                    int e = ctid + i2 * 128;
                    if (e < CG * 16) {
                        int c = e >> 4, qq = e & 15;
                        unsigned long long bits = bitsb[jb][c] >> (4 * qq);
                        float4 v;
                        v.x = (bits & 1ull) ? 1.0f : 0.0f;
                        v.y = (bits & 2ull) ? 1.0f : 0.0f;
                        v.z = (bits & 4ull) ? 1.0f : 0.0f;
                        v.w = (bits & 8ull) ? 1.0f : 0.0f;
                        *(float4*)(obase + ((size_t)c << 11) + t0o + 4 * qq) = v;
                    }
                }
            }
            // 4) drain staged regs -> LDS (next buffers)
            if (st) {
                #pragma unroll
                for (int i2 = 0; i2 < 4; ++i2) {
                    int e = ctid + i2 * 128;
                    if (e < ROWS * 16) {
                        int rr = e >> 4, qq = e & 15;
                        *(float4*)&xs[nbuf][rr][4 * qq] = rv[i2];
                    }
                }
                if (ctid < TPB) {
                    #pragma unroll
                    for (int i2 = 0; i2 < 7; ++i2) kd[nbuf][ctid][i2] = kv[i2];
                }
            }
        } else {
            // scan(k-1): 8-deep double-buffered prefetch, ~10cyc/step chain
            if (k >= 1 && k <= NT) {
                const int p = (k - 1) & 1;
                const int c = tid;
                if (c < CG) {
                    unsigned long long bits = 0ull;
                    double va[8], vb[8];
                    #pragma unroll
                    for (int j2 = 0; j2 < 8; ++j2) va[j2] = Is[p][j2][c];
                    #pragma unroll
                    for (int g = 0; g < 64; g += 16) {
                        #pragma unroll
                        for (int j2 = 0; j2 < 8; ++j2) vb[j2] = Is[p][g + 8 + j2][c];
                        #pragma unroll
                        for (int j2 = 0; j2 < 8; ++j2) {
                            double a2 = va[j2];
                            double cm = a2 - 1.0;
                            double m1 = fma(0.95, mem, a2);
                            double m2 = fma(0.95, mem, cm);
                            mem = r ? m2 : m1;
                            r = mem > 1.0;
                            bits |= (unsigned long long)(r ? 1 : 0) << (g + j2);
                        }
                        if (g + 16 < 64) {
                            #pragma unroll
                            for (int j2 = 0; j2 < 8; ++j2) va[j2] = Is[p][g + 16 + j2][c];
                        }
                        #pragma unroll
                        for (int j2 = 0; j2 < 8; ++j2) {
                            double a2 = vb[j2];
                            double cm = a2 - 1.0;
                            double m1 = fma(0.95, mem, a2);
                            double m2 = fma(0.95, mem, cm);
                            mem = r ? m2 : m1;
                            r = mem > 1.0;
                            bits |= (unsigned long long)(r ? 1 : 0) << (g + 8 + j2);
                        }
                    }
                    bitsb[p][c] = bits;
                }
            }
        }
        __syncthreads();
    }
}

// ---------------------------------------------------------------------------
extern "C" void kernel_launch(void* const* d_in, const int* in_sizes, int n_in,
                              void* d_out, int out_size, void* d_ws, size_t ws_size,
                              hipStream_t stream)
{
    const float* x  = (const float*)d_in[0];   // (32,1,224,2048) f32
    const float* lw = (const float*)d_in[1];   // (1,224) f32
    float* out = (float*)d_out;                // (32,1,224,2048) f32

    double* kernG = (double*)d_ws;             // 65536 * 7 * 8 = 3,670,016 B

    kw<<<dim3(TTT / 64, BB), 256, 0, stream>>>(x, lw, kernG);
    kf<<<dim3(NCG, BB), 192, 0, stream>>>(x, kernG, out);
}

// Round 2
// 152.096 us; speedup vs baseline: 1.0350x; 1.0350x over previous
//
#include <hip/hip_runtime.h>
#include <math.h>

#define BB 32
#define CCH 224
#define TTT 2048
#define TPB 64             // t per tile in kf
#define NT  (TTT/TPB)      // 32 tiles
#define CG  28             // chains (channels) per kf block (halo-optimal)
#define NCG (CCH/CG)       // 8
#define ROWS 40            // CG + 12 halo rows
#define XROW 68            // floats per xs row (64 + 4 pad, 16B-aligned)
#define IROW 29            // f64 per I row (28 + 1 pad)

// ---------------------------------------------------------------------------
// kw: per (b,t): f64 dot over C -> w -> 7 symmetric Gaussian taps (f64).
// block = 64 t x 4 channel-quarters (256 thr), LDS reduce. grid (32,32)
// = 1024 blocks = 16 waves/CU -> load latency hidden. Summation order
// preserved exactly: p_q sequential over its 56 channels, (p0+p1)+(p2+p3).
// ---------------------------------------------------------------------------
__global__ __launch_bounds__(256) void kw(
    const float* __restrict__ x, const float* __restrict__ lw,
    double* __restrict__ kernG)
{
    __shared__ double sp[4][64];
    const int b  = blockIdx.y;
    const int tl = threadIdx.x & 63;
    const int q  = threadIdx.x >> 6;           // channel quarter 0..3
    const int t  = blockIdx.x * 64 + tl;

    const float* xb  = x + (((size_t)(b * CCH + 56 * q)) << 11) + t;
    const float* lwq = lw + 56 * q;

    double p = 0.0;
    #pragma unroll 8
    for (int i = 0; i < 56; ++i)
        p += (double)xb[(size_t)i << 11] * (double)lwq[i];
    sp[q][tl] = p;
    __syncthreads();

    if (threadIdx.x < 64) {
        double acc = (sp[0][tl] + sp[1][tl]) + (sp[2][tl] + sp[3][tl]);

        double w = 5.2 + acc * 9.6;
        w = fmin(fmax(w, 0.4), 10.0);
        double iw2 = 1.0 / (w * w);

        // norm over linspace(-60,60,130): exactly symmetric -> 2x half-sum,
        // terms G^{(2u+1)^2} via power recurrence (2 exps total)
        const double s = 120.0 / 129.0;
        double G  = exp(-0.125 * s * s * iw2);
        double G2 = G * G, G4 = G2 * G2, G8 = G4 * G4;
        double term = G, cmul = G8, norm = G;
        for (int u = 1; u <= 64; ++u) { term *= cmul; cmul *= G8; norm += term; }
        norm *= 2.0;

        double P = exp(-0.5 * iw2), P2 = P * P;
        double a = 1.0, bm = P, inv = 1.0 / norm;
        double* kr = kernG + (size_t)(b * TTT + t) * 7;
        kr[0] = inv;                      // center tap
        #pragma unroll
        for (int d = 1; d <= 6; ++d) {
            a *= bm; bm *= P2;
            kr[d] = a * inv;              // tap at distance d (symmetric)
        }
    }
}

// ---------------------------------------------------------------------------
// kf: fused conv + LIF scan + spike output. grid (8, 32) x 320 threads.
// wave0 = scan (28 chains); waves 1-4 = conv (7 ch each) / stage / out-write.
// CG=28 keeps halo FETCH minimal (53.8 MB); 4 conv waves halve the conv
// wave's intra-phase dependency chain so the scan wave is the critical path.
// Pipeline (1 barrier per phase), slot-by-slot identical to the verified v1:
//   phase k: conv(k)->Is[k&1]; stage(k+1)->xs/kd[(k+1)&1]; scan(k-1) reads
//   Is[(k-1)&1] -> bitsb[(k-1)&1]; out-write(k-2) reads bitsb[k&1].
// ---------------------------------------------------------------------------
__global__ __launch_bounds__(320) void kf(
    const float* __restrict__ x, const double* __restrict__ kernG,
    float* __restrict__ out)
{
    __shared__ __align__(16) float xs[2][ROWS][XROW];      // 21760 B
    __shared__ double kd[2][TPB][7];                       //  7168 B
    __shared__ double Is[2][TPB][IROW];                    // 29696 B
    __shared__ unsigned long long bitsb[2][CG];            //   448 B

    const int b   = blockIdx.y;
    const int cgi = blockIdx.x;
    const int c0  = cgi * CG;
    const int tid = threadIdx.x;
    const int ctid = tid - 64;          // 0..255 for conv waves

    const float*  xbase = x + (((size_t)(b * CCH)) << 11);
    const double* kbase = kernG + (size_t)(b * TTT) * 7;
    float* obase = out + (((size_t)(b * CCH + c0)) << 11);

    double mem = 0.0;   // scan state (wave0 lanes)
    bool   r   = false;

    // ---- prologue: stage tile 0 ----
    if (tid >= 64) {
        #pragma unroll
        for (int i2 = 0; i2 < 3; ++i2) {
            int e = ctid + i2 * 256;
            if (e < ROWS * 16) {
                int rr = e >> 4, q = e & 15;
                int cr = c0 - 6 + rr;
                float4 v = make_float4(0.f, 0.f, 0.f, 0.f);
                if (cr >= 0 && cr < CCH)
                    v = *(const float4*)(xbase + ((size_t)cr << 11) + 4 * q);
                *(float4*)&xs[0][rr][4 * q] = v;
            }
        }
        if (ctid < TPB) {
            const double* kp = kbase + (size_t)ctid * 7;
            #pragma unroll
            for (int i2 = 0; i2 < 7; ++i2) kd[0][ctid][i2] = kp[i2];
        }
    }
    __syncthreads();

    for (int k = 0; k <= NT + 1; ++k) {
        if (tid >= 64) {
            const int buf = k & 1, nbuf = (k + 1) & 1;
            // 1) issue global loads for tile k+1 (latency hidden under conv)
            float4 rv[3]; double kv[7];
            const bool st = (k + 1 <= NT - 1);
            if (st) {
                const int gt0 = (k + 1) * TPB;
                #pragma unroll
                for (int i2 = 0; i2 < 3; ++i2) {
                    int e = ctid + i2 * 256;
                    if (e < ROWS * 16) {
                        int rr = e >> 4, q = e & 15;
                        int cr = c0 - 6 + rr;
                        rv[i2] = make_float4(0.f, 0.f, 0.f, 0.f);
                        if (cr >= 0 && cr < CCH)
                            rv[i2] = *(const float4*)(xbase + ((size_t)cr << 11) + gt0 + 4 * q);
                    }
                }
                if (ctid < TPB) {
                    const double* kp = kbase + (size_t)(gt0 + ctid) * 7;
                    #pragma unroll
                    for (int i2 = 0; i2 < 7; ++i2) kv[i2] = kp[i2];
                }
            }
            // 2) conv(k): thread = (t, quarter) -> 7 channels, sliding 13-row ring
            if (k <= NT - 1) {
                const int t  = ctid & 63;
                const int ch = ctid >> 6;       // 0..3
                const int cb = 7 * ch;
                double kk7[7];
                #pragma unroll
                for (int i2 = 0; i2 < 7; ++i2) kk7[i2] = kd[buf][t][i2];
                float xv[13];
                #pragma unroll
                for (int i2 = 0; i2 < 13; ++i2) xv[i2] = xs[buf][cb + i2][t];
                #pragma unroll
                for (int c = 0; c < 7; ++c) {
                    double acc = 0.0;
                    #pragma unroll
                    for (int kk2 = 0; kk2 < 13; ++kk2) {
                        int d = kk2 < 6 ? 6 - kk2 : kk2 - 6;
                        acc = fma((double)xv[(c + kk2) % 13], kk7[d], acc);
                    }
                    double xvv = (double)xv[(c + 6) % 13];
                    double dd  = xvv - acc;
                    Is[buf][t][cb + c] = xvv - (dd > 0.0 ? dd : 0.0);
                    if (c < 6) xv[c % 13] = xs[buf][cb + c + 13][t];
                }
            }
            // 3) out-write(k-2): coalesced float4 spike stores
            if (k >= 2) {
                const int j = k - 2, jb = j & 1;
                const int t0o = j * TPB;
                #pragma unroll
                for (int i2 = 0; i2 < 2; ++i2) {
                    int e = ctid + i2 * 256;
                    if (e < CG * 16) {
                        int c = e >> 4, q = e & 15;
                        unsigned long long bits = bitsb[jb][c] >> (4 * q);
                        float4 v;
                        v.x = (bits & 1ull) ? 1.0f : 0.0f;
                        v.y = (bits & 2ull) ? 1.0f : 0.0f;
                        v.z = (bits & 4ull) ? 1.0f : 0.0f;
                        v.w = (bits & 8ull) ? 1.0f : 0.0f;
                        *(float4*)(obase + ((size_t)c << 11) + t0o + 4 * q) = v;
                    }
                }
            }
            // 4) drain staged regs -> LDS (next buffers)
            if (st) {
                #pragma unroll
                for (int i2 = 0; i2 < 3; ++i2) {
                    int e = ctid + i2 * 256;
                    if (e < ROWS * 16) {
                        int rr = e >> 4, q = e & 15;
                        *(float4*)&xs[nbuf][rr][4 * q] = rv[i2];
                    }
                }
                if (ctid < TPB) {
                    #pragma unroll
                    for (int i2 = 0; i2 < 7; ++i2) kd[nbuf][ctid][i2] = kv[i2];
                }
            }
        } else {
            // scan(k-1): 8-deep double-buffered prefetch, ~10cyc/step chain
            if (k >= 1 && k <= NT) {
                const int p = (k - 1) & 1;
                const int c = tid;
                if (c < CG) {
                    unsigned long long bits = 0ull;
                    double va[8], vb[8];
                    #pragma unroll
                    for (int j2 = 0; j2 < 8; ++j2) va[j2] = Is[p][j2][c];
                    #pragma unroll
                    for (int g = 0; g < 64; g += 16) {
                        #pragma unroll
                        for (int j2 = 0; j2 < 8; ++j2) vb[j2] = Is[p][g + 8 + j2][c];
                        #pragma unroll
                        for (int j2 = 0; j2 < 8; ++j2) {
                            double a2 = va[j2];
                            double cm = a2 - 1.0;
                            double m1 = fma(0.95, mem, a2);
                            double m2 = fma(0.95, mem, cm);
                            mem = r ? m2 : m1;
                            r = mem > 1.0;
                            bits |= (unsigned long long)(r ? 1 : 0) << (g + j2);
                        }
                        if (g + 16 < 64) {
                            #pragma unroll
                            for (int j2 = 0; j2 < 8; ++j2) va[j2] = Is[p][g + 16 + j2][c];
                        }
                        #pragma unroll
                        for (int j2 = 0; j2 < 8; ++j2) {
                            double a2 = vb[j2];
                            double cm = a2 - 1.0;
                            double m1 = fma(0.95, mem, a2);
                            double m2 = fma(0.95, mem, cm);
                            mem = r ? m2 : m1;
                            r = mem > 1.0;
                            bits |= (unsigned long long)(r ? 1 : 0) << (g + 8 + j2);
                        }
                    }
                    bitsb[p][c] = bits;
                }
            }
        }
        __syncthreads();
    }
}

// ---------------------------------------------------------------------------
extern "C" void kernel_launch(void* const* d_in, const int* in_sizes, int n_in,
                              void* d_out, int out_size, void* d_ws, size_t ws_size,
                              hipStream_t stream)
{
    const float* x  = (const float*)d_in[0];   // (32,1,224,2048) f32
    const float* lw = (const float*)d_in[1];   // (1,224) f32
    float* out = (float*)d_out;                // (32,1,224,2048) f32

    double* kernG = (double*)d_ws;             // 65536 * 7 * 8 = 3,670,016 B

    kw<<<dim3(TTT / 64, BB), 256, 0, stream>>>(x, lw, kernG);
    kf<<<dim3(NCG, BB), 320, 0, stream>>>(x, kernG, out);
}

// Round 3
// 146.414 us; speedup vs baseline: 1.0752x; 1.0388x over previous
//
#include <hip/hip_runtime.h>
#include <math.h>

#define BB 32
#define CCH 224
#define TTT 2048
#define TPB 64             // t per tile in kf
#define NT  (TTT/TPB)      // 32 tiles
#define CG  28             // chains (channels) per kf block (halo-optimal)
#define NCG (CCH/CG)       // 8
#define ROWS 40            // CG + 12 halo rows
#define XROW 68            // floats per xs row (64 + 4 pad, 16B-aligned)
#define IROW 29            // f64 per I row (28 + 1 pad)

// LDS-only barrier: cross-wave deps in kf are all through LDS. Avoids the
// __syncthreads() vmcnt(0) drain that stalls on store-commit and kills
// cross-barrier load pipelining (guide T4: never drain vmcnt at barriers).
__device__ __forceinline__ void bar_lds() {
    asm volatile("s_waitcnt lgkmcnt(0)" ::: "memory");
    __builtin_amdgcn_s_barrier();
    asm volatile("" ::: "memory");
}

// ---------------------------------------------------------------------------
// kw: per (b,t): f64 dot over C -> w -> 7 symmetric Gaussian taps (f64).
// block = 64 t x 4 channel-quarters (256 thr), LDS reduce. grid (32,32)
// = 1024 blocks = 16 waves/CU -> load latency hidden. Summation order
// preserved exactly: p_q sequential over its 56 channels, (p0+p1)+(p2+p3).
// ---------------------------------------------------------------------------
__global__ __launch_bounds__(256) void kw(
    const float* __restrict__ x, const float* __restrict__ lw,
    double* __restrict__ kernG)
{
    __shared__ double sp[4][64];
    const int b  = blockIdx.y;
    const int tl = threadIdx.x & 63;
    const int q  = threadIdx.x >> 6;           // channel quarter 0..3
    const int t  = blockIdx.x * 64 + tl;

    const float* xb  = x + (((size_t)(b * CCH + 56 * q)) << 11) + t;
    const float* lwq = lw + 56 * q;

    double p = 0.0;
    #pragma unroll 8
    for (int i = 0; i < 56; ++i)
        p += (double)xb[(size_t)i << 11] * (double)lwq[i];
    sp[q][tl] = p;
    __syncthreads();

    if (threadIdx.x < 64) {
        double acc = (sp[0][tl] + sp[1][tl]) + (sp[2][tl] + sp[3][tl]);

        double w = 5.2 + acc * 9.6;
        w = fmin(fmax(w, 0.4), 10.0);
        double iw2 = 1.0 / (w * w);

        // norm over linspace(-60,60,130): exactly symmetric -> 2x half-sum,
        // terms G^{(2u+1)^2} via power recurrence (2 exps total)
        const double s = 120.0 / 129.0;
        double G  = exp(-0.125 * s * s * iw2);
        double G2 = G * G, G4 = G2 * G2, G8 = G4 * G4;
        double term = G, cmul = G8, norm = G;
        for (int u = 1; u <= 64; ++u) { term *= cmul; cmul *= G8; norm += term; }
        norm *= 2.0;

        double P = exp(-0.5 * iw2), P2 = P * P;
        double a = 1.0, bm = P, inv = 1.0 / norm;
        double* kr = kernG + (size_t)(b * TTT + t) * 7;
        kr[0] = inv;                      // center tap
        #pragma unroll
        for (int d = 1; d <= 6; ++d) {
            a *= bm; bm *= P2;
            kr[d] = a * inv;              // tap at distance d (symmetric)
        }
    }
}

// ---------------------------------------------------------------------------
// kf: fused conv + LIF scan + spike output. grid (8, 32) x 320 threads.
// wave0 = scan (28 chains); waves 1-4 = conv (7 ch each) / stage / out-write.
// v4: LDS-only barriers + 2-phase-deep prefetch. Phase k (conv waves):
//   (a) drain rv (tile k+1, loaded in phase k-1, ~1 phase old -> no stall)
//       into xs/kd[(k+1)&1]
//   (b) issue global loads for tile k+2 -> rv (a full phase to cover latency,
//       loads stay in flight ACROSS the barrier)
//   (c) out-write(k-2): fire-and-forget stores (no barrier drain ever)
//   (d) conv(k): xs/kd[k&1] -> Is[k&1]
// scan wave: scan(k-1) reads Is[(k-1)&1] -> bitsb[(k-1)&1], setprio(1)
// around the serial chain. Buffer disjointness per phase verified:
//   writes: xs/kd[nbuf], Is[buf], bitsb[nbuf]; reads: xs/kd[buf], Is[nbuf]
//   (written phase k-1), bitsb[buf] (written phase k-2). All barrier-separated.
// ---------------------------------------------------------------------------
__global__ __launch_bounds__(320) void kf(
    const float* __restrict__ x, const double* __restrict__ kernG,
    float* __restrict__ out)
{
    __shared__ __align__(16) float xs[2][ROWS][XROW];      // 21760 B
    __shared__ double kd[2][TPB][7];                       //  7168 B
    __shared__ double Is[2][TPB][IROW];                    // 29696 B
    __shared__ unsigned long long bitsb[2][CG];            //   448 B

    const int b   = blockIdx.y;
    const int cgi = blockIdx.x;
    const int c0  = cgi * CG;
    const int tid = threadIdx.x;
    const int ctid = tid - 64;          // 0..255 for conv waves

    const float*  xbase = x + (((size_t)(b * CCH)) << 11);
    const double* kbase = kernG + (size_t)(b * TTT) * 7;
    float* obase = out + (((size_t)(b * CCH + c0)) << 11);

    double mem = 0.0;   // scan state (wave0 lanes)
    bool   r   = false;

    float4 rv[3]; double kv[7];

    // ---- prologue: stage tile 0 directly; issue rv loads for tile 1 ----
    if (tid >= 64) {
        #pragma unroll
        for (int i2 = 0; i2 < 3; ++i2) {
            int e = ctid + i2 * 256;
            if (e < ROWS * 16) {
                int rr = e >> 4, q = e & 15;
                int cr = c0 - 6 + rr;
                float4 v = make_float4(0.f, 0.f, 0.f, 0.f);
                if (cr >= 0 && cr < CCH)
                    v = *(const float4*)(xbase + ((size_t)cr << 11) + 4 * q);
                *(float4*)&xs[0][rr][4 * q] = v;
            }
        }
        if (ctid < TPB) {
            const double* kp = kbase + (size_t)ctid * 7;
            #pragma unroll
            for (int i2 = 0; i2 < 7; ++i2) kd[0][ctid][i2] = kp[i2];
        }
        // issue tile-1 loads into rv
        {
            const int gt0 = TPB;
            #pragma unroll
            for (int i2 = 0; i2 < 3; ++i2) {
                int e = ctid + i2 * 256;
                if (e < ROWS * 16) {
                    int rr = e >> 4, q = e & 15;
                    int cr = c0 - 6 + rr;
                    rv[i2] = make_float4(0.f, 0.f, 0.f, 0.f);
                    if (cr >= 0 && cr < CCH)
                        rv[i2] = *(const float4*)(xbase + ((size_t)cr << 11) + gt0 + 4 * q);
                }
            }
            if (ctid < TPB) {
                const double* kp = kbase + (size_t)(gt0 + ctid) * 7;
                #pragma unroll
                for (int i2 = 0; i2 < 7; ++i2) kv[i2] = kp[i2];
            }
        }
    }
    bar_lds();

    for (int k = 0; k <= NT + 1; ++k) {
        if (tid >= 64) {
            const int buf = k & 1, nbuf = (k + 1) & 1;
            // (a) drain rv (tile k+1) -> LDS next buffers; loads are 1 phase old
            if (k + 1 <= NT - 1) {
                #pragma unroll
                for (int i2 = 0; i2 < 3; ++i2) {
                    int e = ctid + i2 * 256;
                    if (e < ROWS * 16) {
                        int rr = e >> 4, q = e & 15;
                        *(float4*)&xs[nbuf][rr][4 * q] = rv[i2];
                    }
                }
                if (ctid < TPB) {
                    #pragma unroll
                    for (int i2 = 0; i2 < 7; ++i2) kd[nbuf][ctid][i2] = kv[i2];
                }
            }
            // (b) issue global loads for tile k+2 -> rv
            if (k + 2 <= NT - 1) {
                const int gt0 = (k + 2) * TPB;
                #pragma unroll
                for (int i2 = 0; i2 < 3; ++i2) {
                    int e = ctid + i2 * 256;
                    if (e < ROWS * 16) {
                        int rr = e >> 4, q = e & 15;
                        int cr = c0 - 6 + rr;
                        rv[i2] = make_float4(0.f, 0.f, 0.f, 0.f);
                        if (cr >= 0 && cr < CCH)
                            rv[i2] = *(const float4*)(xbase + ((size_t)cr << 11) + gt0 + 4 * q);
                    }
                }
                if (ctid < TPB) {
                    const double* kp = kbase + (size_t)(gt0 + ctid) * 7;
                    #pragma unroll
                    for (int i2 = 0; i2 < 7; ++i2) kv[i2] = kp[i2];
                }
            }
            // (c) out-write(k-2): fire-and-forget coalesced float4 spike stores
            if (k >= 2) {
                const int j = k - 2, jb = j & 1;
                const int t0o = j * TPB;
                #pragma unroll
                for (int i2 = 0; i2 < 2; ++i2) {
                    int e = ctid + i2 * 256;
                    if (e < CG * 16) {
                        int c = e >> 4, q = e & 15;
                        unsigned long long bits = bitsb[jb][c] >> (4 * q);
                        float4 v;
                        v.x = (bits & 1ull) ? 1.0f : 0.0f;
                        v.y = (bits & 2ull) ? 1.0f : 0.0f;
                        v.z = (bits & 4ull) ? 1.0f : 0.0f;
                        v.w = (bits & 8ull) ? 1.0f : 0.0f;
                        *(float4*)(obase + ((size_t)c << 11) + t0o + 4 * q) = v;
                    }
                }
            }
            // (d) conv(k): thread = (t, quarter) -> 7 channels, sliding ring
            if (k <= NT - 1) {
                const int t  = ctid & 63;
                const int ch = ctid >> 6;       // 0..3
                const int cb = 7 * ch;
                double kk7[7];
                #pragma unroll
                for (int i2 = 0; i2 < 7; ++i2) kk7[i2] = kd[buf][t][i2];
                float xv[13];
                #pragma unroll
                for (int i2 = 0; i2 < 13; ++i2) xv[i2] = xs[buf][cb + i2][t];
                #pragma unroll
                for (int c = 0; c < 7; ++c) {
                    double acc = 0.0;
                    #pragma unroll
                    for (int kk2 = 0; kk2 < 13; ++kk2) {
                        int d = kk2 < 6 ? 6 - kk2 : kk2 - 6;
                        acc = fma((double)xv[(c + kk2) % 13], kk7[d], acc);
                    }
                    double xvv = (double)xv[(c + 6) % 13];
                    double dd  = xvv - acc;
                    Is[buf][t][cb + c] = xvv - (dd > 0.0 ? dd : 0.0);
                    if (c < 6) xv[c % 13] = xs[buf][cb + c + 13][t];
                }
            }
        } else {
            // scan(k-1): 8-deep double-buffered prefetch, serial LIF chain
            if (k >= 1 && k <= NT) {
                const int p = (k - 1) & 1;
                const int c = tid;
                __builtin_amdgcn_s_setprio(1);
                if (c < CG) {
                    unsigned long long bits = 0ull;
                    double va[8], vb[8];
                    #pragma unroll
                    for (int j2 = 0; j2 < 8; ++j2) va[j2] = Is[p][j2][c];
                    #pragma unroll
                    for (int g = 0; g < 64; g += 16) {
                        #pragma unroll
                        for (int j2 = 0; j2 < 8; ++j2) vb[j2] = Is[p][g + 8 + j2][c];
                        #pragma unroll
                        for (int j2 = 0; j2 < 8; ++j2) {
                            double a2 = va[j2];
                            double cm = a2 - 1.0;
                            double m1 = fma(0.95, mem, a2);
                            double m2 = fma(0.95, mem, cm);
                            mem = r ? m2 : m1;
                            r = mem > 1.0;
                            bits |= (unsigned long long)(r ? 1 : 0) << (g + j2);
                        }
                        if (g + 16 < 64) {
                            #pragma unroll
                            for (int j2 = 0; j2 < 8; ++j2) va[j2] = Is[p][g + 16 + j2][c];
                        }
                        #pragma unroll
                        for (int j2 = 0; j2 < 8; ++j2) {
                            double a2 = vb[j2];
                            double cm = a2 - 1.0;
                            double m1 = fma(0.95, mem, a2);
                            double m2 = fma(0.95, mem, cm);
                            mem = r ? m2 : m1;
                            r = mem > 1.0;
                            bits |= (unsigned long long)(r ? 1 : 0) << (g + 8 + j2);
                        }
                    }
                    bitsb[p][c] = bits;
                }
                __builtin_amdgcn_s_setprio(0);
            }
        }
        bar_lds();
    }
}

// ---------------------------------------------------------------------------
extern "C" void kernel_launch(void* const* d_in, const int* in_sizes, int n_in,
                              void* d_out, int out_size, void* d_ws, size_t ws_size,
                              hipStream_t stream)
{
    const float* x  = (const float*)d_in[0];   // (32,1,224,2048) f32
    const float* lw = (const float*)d_in[1];   // (1,224) f32
    float* out = (float*)d_out;                // (32,1,224,2048) f32

    double* kernG = (double*)d_ws;             // 65536 * 7 * 8 = 3,670,016 B

    kw<<<dim3(TTT / 64, BB), 256, 0, stream>>>(x, lw, kernG);
    kf<<<dim3(NCG, BB), 320, 0, stream>>>(x, kernG, out);
}

// Round 4
// 146.028 us; speedup vs baseline: 1.0781x; 1.0026x over previous
//
#include <hip/hip_runtime.h>
#include <math.h>

#define BB 32
#define CCH 224
#define TTT 2048
#define TPB 64             // t per tile in kf
#define NT  (TTT/TPB)      // 32 tiles
#define CG  28             // chains (channels) per kf block (halo-optimal)
#define NCG (CCH/CG)       // 8
#define ROWS 40            // CG + 12 halo rows
#define XROW 68            // floats per xs row (64 + 4 pad, 16B-aligned)
#define IROW 29            // f64 per I row (28 + 1 pad)
#define CPW 4              // channels per conv thread (7 conv waves)
#define CTH 448            // conv threads (waves 1..7)

// LDS-only barrier: cross-wave deps in kf are all through LDS. Avoids the
// __syncthreads() vmcnt(0) drain (stores fire-and-forget; prefetch loads
// stay in flight across the barrier — guide T4).
__device__ __forceinline__ void bar_lds() {
    asm volatile("s_waitcnt lgkmcnt(0)" ::: "memory");
    __builtin_amdgcn_s_barrier();
    asm volatile("" ::: "memory");
}

// ---------------------------------------------------------------------------
// kw: per (b,t): f64 dot over C -> w -> 7 symmetric Gaussian taps (f64).
// block = 64 t x 4 channel-quarters (256 thr), LDS reduce. grid (32,32)
// = 1024 blocks = 16 waves/CU. Summation order preserved exactly:
// p_q sequential over its 56 channels, (p0+p1)+(p2+p3).
// ---------------------------------------------------------------------------
__global__ __launch_bounds__(256) void kw(
    const float* __restrict__ x, const float* __restrict__ lw,
    double* __restrict__ kernG)
{
    __shared__ double sp[4][64];
    const int b  = blockIdx.y;
    const int tl = threadIdx.x & 63;
    const int q  = threadIdx.x >> 6;           // channel quarter 0..3
    const int t  = blockIdx.x * 64 + tl;

    const float* xb  = x + (((size_t)(b * CCH + 56 * q)) << 11) + t;
    const float* lwq = lw + 56 * q;

    double p = 0.0;
    #pragma unroll 8
    for (int i = 0; i < 56; ++i)
        p += (double)xb[(size_t)i << 11] * (double)lwq[i];
    sp[q][tl] = p;
    __syncthreads();

    if (threadIdx.x < 64) {
        double acc = (sp[0][tl] + sp[1][tl]) + (sp[2][tl] + sp[3][tl]);

        double w = 5.2 + acc * 9.6;
        w = fmin(fmax(w, 0.4), 10.0);
        double iw2 = 1.0 / (w * w);

        // norm over linspace(-60,60,130): exactly symmetric -> 2x half-sum,
        // terms G^{(2u+1)^2} via power recurrence (2 exps total)
        const double s = 120.0 / 129.0;
        double G  = exp(-0.125 * s * s * iw2);
        double G2 = G * G, G4 = G2 * G2, G8 = G4 * G4;
        double term = G, cmul = G8, norm = G;
        for (int u = 1; u <= 64; ++u) { term *= cmul; cmul *= G8; norm += term; }
        norm *= 2.0;

        double P = exp(-0.5 * iw2), P2 = P * P;
        double a = 1.0, bm = P, inv = 1.0 / norm;
        double* kr = kernG + (size_t)(b * TTT + t) * 7;
        kr[0] = inv;                      // center tap
        #pragma unroll
        for (int d = 1; d <= 6; ++d) {
            a *= bm; bm *= P2;
            kr[d] = a * inv;              // tap at distance d (symmetric)
        }
    }
}

// ---------------------------------------------------------------------------
// kf: fused conv + LIF scan + spike output. grid (8, 32) x 512 threads.
// wave0 = scan (28 chains, fused select-then-fma step); waves 1-7 = conv
// (4 ch/thread) / stage / out-write. Every SIMD hosts exactly 2 waves;
// SIMD0 = scan + one light conv wave (issue-balance is the phase limiter).
// Phase k (conv waves):
//   (a) drain rv (tile k+1, loaded phase k-1) -> xs/kd[(k+1)&1]
//   (b) issue global loads tile k+2 -> rv (in flight across barriers)
//   (c) out-write(k-2): fire-and-forget float4 stores (1 per thread)
//   (d) conv(k): xs/kd[k&1] -> Is[k&1]  (xv held as f64: cvt hoisted)
// scan wave: scan(k-1) reads Is[(k-1)&1] -> bitsb[(k-1)&1].
// Buffer disjointness per phase identical to verified v4 schedule.
// ---------------------------------------------------------------------------
__global__ __launch_bounds__(512) void kf(
    const float* __restrict__ x, const double* __restrict__ kernG,
    float* __restrict__ out)
{
    __shared__ __align__(16) float xs[2][ROWS][XROW];      // 21760 B
    __shared__ double kd[2][TPB][7];                       //  7168 B
    __shared__ double Is[2][TPB][IROW];                    // 29696 B
    __shared__ unsigned long long bitsb[2][CG];            //   448 B

    const int b   = blockIdx.y;
    const int cgi = blockIdx.x;
    const int c0  = cgi * CG;
    const int tid = threadIdx.x;
    const int ctid = tid - 64;          // 0..447 for conv waves

    const float*  xbase = x + (((size_t)(b * CCH)) << 11);
    const double* kbase = kernG + (size_t)(b * TTT) * 7;
    float* obase = out + (((size_t)(b * CCH + c0)) << 11);

    double mem = 0.0;   // scan state (wave0 lanes)
    bool   r   = false;

    float4 rv[2]; double kv[7];

    // ---- prologue: stage tile 0 directly; issue rv loads for tile 1 ----
    if (tid >= 64) {
        #pragma unroll
        for (int i2 = 0; i2 < 2; ++i2) {
            int e = ctid + i2 * CTH;
            if (e < ROWS * 16) {
                int rr = e >> 4, q = e & 15;
                int cr = c0 - 6 + rr;
                float4 v = make_float4(0.f, 0.f, 0.f, 0.f);
                if (cr >= 0 && cr < CCH)
                    v = *(const float4*)(xbase + ((size_t)cr << 11) + 4 * q);
                *(float4*)&xs[0][rr][4 * q] = v;
            }
        }
        if (ctid < TPB) {
            const double* kp = kbase + (size_t)ctid * 7;
            #pragma unroll
            for (int i2 = 0; i2 < 7; ++i2) kd[0][ctid][i2] = kp[i2];
        }
        // issue tile-1 loads into rv
        {
            const int gt0 = TPB;
            #pragma unroll
            for (int i2 = 0; i2 < 2; ++i2) {
                int e = ctid + i2 * CTH;
                if (e < ROWS * 16) {
                    int rr = e >> 4, q = e & 15;
                    int cr = c0 - 6 + rr;
                    rv[i2] = make_float4(0.f, 0.f, 0.f, 0.f);
                    if (cr >= 0 && cr < CCH)
                        rv[i2] = *(const float4*)(xbase + ((size_t)cr << 11) + gt0 + 4 * q);
                }
            }
            if (ctid < TPB) {
                const double* kp = kbase + (size_t)(gt0 + ctid) * 7;
                #pragma unroll
                for (int i2 = 0; i2 < 7; ++i2) kv[i2] = kp[i2];
            }
        }
    }
    bar_lds();

    for (int k = 0; k <= NT + 1; ++k) {
        if (tid >= 64) {
            const int buf = k & 1, nbuf = (k + 1) & 1;
            // (a) drain rv (tile k+1) -> LDS next buffers
            if (k + 1 <= NT - 1) {
                #pragma unroll
                for (int i2 = 0; i2 < 2; ++i2) {
                    int e = ctid + i2 * CTH;
                    if (e < ROWS * 16) {
                        int rr = e >> 4, q = e & 15;
                        *(float4*)&xs[nbuf][rr][4 * q] = rv[i2];
                    }
                }
                if (ctid < TPB) {
                    #pragma unroll
                    for (int i2 = 0; i2 < 7; ++i2) kd[nbuf][ctid][i2] = kv[i2];
                }
            }
            // (b) issue global loads for tile k+2 -> rv
            if (k + 2 <= NT - 1) {
                const int gt0 = (k + 2) * TPB;
                #pragma unroll
                for (int i2 = 0; i2 < 2; ++i2) {
                    int e = ctid + i2 * CTH;
                    if (e < ROWS * 16) {
                        int rr = e >> 4, q = e & 15;
                        int cr = c0 - 6 + rr;
                        rv[i2] = make_float4(0.f, 0.f, 0.f, 0.f);
                        if (cr >= 0 && cr < CCH)
                            rv[i2] = *(const float4*)(xbase + ((size_t)cr << 11) + gt0 + 4 * q);
                    }
                }
                if (ctid < TPB) {
                    const double* kp = kbase + (size_t)(gt0 + ctid) * 7;
                    #pragma unroll
                    for (int i2 = 0; i2 < 7; ++i2) kv[i2] = kp[i2];
                }
            }
            // (c) out-write(k-2): fire-and-forget stores, exactly 1 per thread
            if (k >= 2) {
                const int j = k - 2, jb = j & 1;
                const int t0o = j * TPB;
                int c = ctid >> 4, q = ctid & 15;          // 448 = 28*16 slots
                unsigned long long bits = bitsb[jb][c] >> (4 * q);
                float4 v;
                v.x = (bits & 1ull) ? 1.0f : 0.0f;
                v.y = (bits & 2ull) ? 1.0f : 0.0f;
                v.z = (bits & 4ull) ? 1.0f : 0.0f;
                v.w = (bits & 8ull) ? 1.0f : 0.0f;
                *(float4*)(obase + ((size_t)c << 11) + t0o + 4 * q) = v;
            }
            // (d) conv(k): thread = (t, group) -> 4 channels, sliding ring
            if (k <= NT - 1) {
                const int t  = ctid & 63;
                const int g  = ctid >> 6;       // 0..6
                const int cb = CPW * g;
                double kk7[7];
                #pragma unroll
                for (int i2 = 0; i2 < 7; ++i2) kk7[i2] = kd[buf][t][i2];
                double xv[13];                  // f64: convert once per element
                #pragma unroll
                for (int i2 = 0; i2 < 13; ++i2) xv[i2] = (double)xs[buf][cb + i2][t];
                #pragma unroll
                for (int c = 0; c < CPW; ++c) {
                    double acc = 0.0;
                    #pragma unroll
                    for (int kk2 = 0; kk2 < 13; ++kk2) {
                        int d = kk2 < 6 ? 6 - kk2 : kk2 - 6;
                        acc = fma(xv[(c + kk2) % 13], kk7[d], acc);
                    }
                    double xvv = xv[(c + 6) % 13];
                    double dd  = xvv - acc;
                    Is[buf][t][cb + c] = xvv - (dd > 0.0 ? dd : 0.0);
                    if (c < CPW - 1) xv[c % 13] = (double)xs[buf][cb + c + 13][t];
                }
            }
        } else {
            // scan(k-1): fused select-then-fma LIF step (bit-identical to
            // compute-both-then-select), a-1 precomputed off-chain.
            if (k >= 1 && k <= NT) {
                const int p = (k - 1) & 1;
                const int c = tid;
                __builtin_amdgcn_s_setprio(1);
                if (c < CG) {
                    unsigned long long bits = 0ull;
                    double va[8], vb[8], ca[8], cb2[8];
                    #pragma unroll
                    for (int j2 = 0; j2 < 8; ++j2) va[j2] = Is[p][j2][c];
                    #pragma unroll
                    for (int j2 = 0; j2 < 8; ++j2) ca[j2] = va[j2] - 1.0;
                    #pragma unroll
                    for (int g = 0; g < 64; g += 16) {
                        #pragma unroll
                        for (int j2 = 0; j2 < 8; ++j2) vb[j2] = Is[p][g + 8 + j2][c];
                        #pragma unroll
                        for (int j2 = 0; j2 < 8; ++j2) cb2[j2] = vb[j2] - 1.0;
                        #pragma unroll
                        for (int j2 = 0; j2 < 8; ++j2) {
                            double ax = r ? ca[j2] : va[j2];
                            mem = fma(0.95, mem, ax);
                            r = mem > 1.0;
                            bits |= (unsigned long long)(r ? 1 : 0) << (g + j2);
                        }
                        if (g + 16 < 64) {
                            #pragma unroll
                            for (int j2 = 0; j2 < 8; ++j2) va[j2] = Is[p][g + 16 + j2][c];
                            #pragma unroll
                            for (int j2 = 0; j2 < 8; ++j2) ca[j2] = va[j2] - 1.0;
                        }
                        #pragma unroll
                        for (int j2 = 0; j2 < 8; ++j2) {
                            double ax = r ? cb2[j2] : vb[j2];
                            mem = fma(0.95, mem, ax);
                            r = mem > 1.0;
                            bits |= (unsigned long long)(r ? 1 : 0) << (g + 8 + j2);
                        }
                    }
                    bitsb[p][c] = bits;
                }
                __builtin_amdgcn_s_setprio(0);
            }
        }
        bar_lds();
    }
}

// ---------------------------------------------------------------------------
extern "C" void kernel_launch(void* const* d_in, const int* in_sizes, int n_in,
                              void* d_out, int out_size, void* d_ws, size_t ws_size,
                              hipStream_t stream)
{
    const float* x  = (const float*)d_in[0];   // (32,1,224,2048) f32
    const float* lw = (const float*)d_in[1];   // (1,224) f32
    float* out = (float*)d_out;                // (32,1,224,2048) f32

    double* kernG = (double*)d_ws;             // 65536 * 7 * 8 = 3,670,016 B

    kw<<<dim3(TTT / 64, BB), 256, 0, stream>>>(x, lw, kernG);
    kf<<<dim3(NCG, BB), 512, 0, stream>>>(x, kernG, out);
}

// Round 5
// 145.389 us; speedup vs baseline: 1.0828x; 1.0044x over previous
//
#include <hip/hip_runtime.h>
#include <math.h>

#define BB 32
#define CCH 224
#define TTT 2048
#define TPB 128            // t per tile in kf (was 64: halves barrier count)
#define NT  (TTT/TPB)      // 16 tiles -> 18 phases
#define CG  28             // chains (channels) per kf block (halo-optimal)
#define NCG (CCH/CG)       // 8
#define IROW 29            // f64 per I row (28 + 1 pad; 2-way banks on scan reads)
#define CPW 4              // channels per conv thread (7 conv waves)

// LDS-only barrier: cross-wave deps in kf are all through LDS (Is, bitsb).
// Stores stay fire-and-forget; prefetch loads stay in flight across barriers.
__device__ __forceinline__ void bar_lds() {
    asm volatile("s_waitcnt lgkmcnt(0)" ::: "memory");
    __builtin_amdgcn_s_barrier();
    asm volatile("" ::: "memory");
}

// ---------------------------------------------------------------------------
// kw: per (b,t): f64 dot over C -> w -> 7 symmetric Gaussian taps (f64).
// block = 64 t x 4 channel-quarters (256 thr), LDS reduce; ~5 TB/s read —
// at its memory roofline, unchanged. Summation order preserved exactly.
// ---------------------------------------------------------------------------
__global__ __launch_bounds__(256) void kw(
    const float* __restrict__ x, const float* __restrict__ lw,
    double* __restrict__ kernG)
{
    __shared__ double sp[4][64];
    const int b  = blockIdx.y;
    const int tl = threadIdx.x & 63;
    const int q  = threadIdx.x >> 6;           // channel quarter 0..3
    const int t  = blockIdx.x * 64 + tl;

    const float* xb  = x + (((size_t)(b * CCH + 56 * q)) << 11) + t;
    const float* lwq = lw + 56 * q;

    double p = 0.0;
    #pragma unroll 8
    for (int i = 0; i < 56; ++i)
        p += (double)xb[(size_t)i << 11] * (double)lwq[i];
    sp[q][tl] = p;
    __syncthreads();

    if (threadIdx.x < 64) {
        double acc = (sp[0][tl] + sp[1][tl]) + (sp[2][tl] + sp[3][tl]);

        double w = 5.2 + acc * 9.6;
        w = fmin(fmax(w, 0.4), 10.0);
        double iw2 = 1.0 / (w * w);

        // norm over linspace(-60,60,130): symmetric -> 2x half-sum,
        // terms G^{(2u+1)^2} via power recurrence (2 exps total)
        const double s = 120.0 / 129.0;
        double G  = exp(-0.125 * s * s * iw2);
        double G2 = G * G, G4 = G2 * G2, G8 = G4 * G4;
        double term = G, cmul = G8, norm = G;
        for (int u = 1; u <= 64; ++u) { term *= cmul; cmul *= G8; norm += term; }
        norm *= 2.0;

        double P = exp(-0.5 * iw2), P2 = P * P;
        double a = 1.0, bm = P, inv = 1.0 / norm;
        double* kr = kernG + (size_t)(b * TTT + t) * 7;
        kr[0] = inv;                      // center tap
        #pragma unroll
        for (int d = 1; d <= 6; ++d) {
            a *= bm; bm *= P2;
            kr[d] = a * inv;              // tap at distance d (symmetric)
        }
    }
}

// ---------------------------------------------------------------------------
// kf v5: fused conv + LIF scan + spikes. grid (8,32) x 512 threads.
// TPB=128 -> 18 barrier phases (was 34). NO x/kern LDS staging: each conv
// thread keeps its 16 halo rows x 2 t-halves in registers, loaded 2 phases
// ahead (ping-pong reg sets A/B, statically indexed). Each per-row load is a
// fully-coalesced wave read of 64 consecutive floats; halo overlap between
// conv waves is absorbed by L1/L2 (FETCH unchanged). LDS = Is (f64) + bitsb.
// Phase k: out-write(k-2) -> conv(k): regs -> Is[k&1] -> issue loads(k+2);
// scan wave: scan(k-1): Is[(k-1)&1] -> bitsb[(k-1)&1]. One barrier per phase.
// Scan step: both-fma-then-select (chain = fma+sel; cmp off-path), values
// bit-identical to all previous rounds.
// ---------------------------------------------------------------------------
__global__ __launch_bounds__(512) void kf(
    const float* __restrict__ x, const double* __restrict__ kernG,
    float* __restrict__ out)
{
    __shared__ double Is[2][TPB][IROW];                // 59392 B
    __shared__ unsigned long long bitsb[2][CG][2];     //   896 B

    const int b   = blockIdx.y;
    const int cgi = blockIdx.x;
    const int c0  = cgi * CG;
    const int tid = threadIdx.x;
    const int ctid = tid - 64;          // 0..447 for conv waves

    const float*  xbase = x + (((size_t)(b * CCH)) << 11);
    const double* kbase = kernG + (size_t)(b * TTT) * 7;
    float* obase = out + (((size_t)(b * CCH + c0)) << 11);

    double mem = 0.0;   // scan state (wave0 lanes)
    bool   r   = false;

    const int tl = ctid & 63;           // conv lane t within half
    const int g  = ctid >> 6;           // conv wave group 0..6
    const int cb = CPW * g;             // first channel (relative) of group

    // issue all global loads for one tile into a reg set (conv waves only)
    auto issue = [&](int tile, float (&rv)[2][16], double (&kv)[2][7]) {
        const int gt0 = tile * TPB;
        #pragma unroll
        for (int h = 0; h < 2; ++h) {
            const int tt = gt0 + tl + 64 * h;
            #pragma unroll
            for (int i = 0; i < 16; ++i) {
                int cr = c0 + cb - 6 + i;
                rv[h][i] = (cr >= 0 && cr < CCH)
                         ? xbase[((size_t)cr << 11) + tt] : 0.f;
            }
            const double* kp = kbase + (size_t)tt * 7;
            #pragma unroll
            for (int i = 0; i < 7; ++i) kv[h][i] = kp[i];
        }
    };

    auto phase = [&](int k, float (&rv)[2][16], double (&kv)[2][7]) {
        if (tid >= 64) {
            const int buf = k & 1;
            // (1) out-write(k-2): fire-and-forget coalesced float4 stores
            if (k >= 2) {
                const int j = k - 2, jb = j & 1;
                const int t0o = j * TPB;
                const int c = ctid >> 4, q = ctid & 15;
                #pragma unroll
                for (int h = 0; h < 2; ++h) {
                    unsigned long long bits = bitsb[jb][c][h] >> (4 * q);
                    float4 v;
                    v.x = (bits & 1ull) ? 1.0f : 0.0f;
                    v.y = (bits & 2ull) ? 1.0f : 0.0f;
                    v.z = (bits & 4ull) ? 1.0f : 0.0f;
                    v.w = (bits & 8ull) ? 1.0f : 0.0f;
                    *(float4*)(obase + ((size_t)c << 11) + t0o + 64 * h + 4 * q) = v;
                }
            }
            // (2) conv(k): registers -> Is[buf]; two t-halves sequentially
            if (k <= NT - 1) {
                #pragma unroll
                for (int h = 0; h < 2; ++h) {
                    double kk7[7];
                    #pragma unroll
                    for (int i = 0; i < 7; ++i) kk7[i] = kv[h][i];
                    double xv[16];
                    #pragma unroll
                    for (int i = 0; i < 16; ++i) xv[i] = (double)rv[h][i];
                    #pragma unroll
                    for (int c = 0; c < CPW; ++c) {
                        double acc = 0.0;
                        #pragma unroll
                        for (int kk = 0; kk < 13; ++kk) {
                            int d = kk < 6 ? 6 - kk : kk - 6;
                            acc = fma(xv[c + kk], kk7[d], acc);
                        }
                        double xvv = xv[c + 6];
                        double dd  = xvv - acc;
                        Is[buf][tl + 64 * h][cb + c] = xvv - (dd > 0.0 ? dd : 0.0);
                    }
                }
            }
            // (3) issue loads for tile k+2 (land during phase k+1, used k+2)
            if (k + 2 <= NT - 1) issue(k + 2, rv, kv);
        } else {
            // scan(k-1): 128 LIF steps, both-fma-then-select, 8-deep prefetch
            if (k >= 1 && k <= NT) {
                const int p = (k - 1) & 1;
                const int c = tid;
                __builtin_amdgcn_s_setprio(1);
                if (c < CG) {
                    unsigned long long bits0 = 0ull, bits1 = 0ull;
                    double va[8], vb8[8], ca[8], cb2[8];
                    #pragma unroll
                    for (int j2 = 0; j2 < 8; ++j2) va[j2] = Is[p][j2][c];
                    #pragma unroll
                    for (int j2 = 0; j2 < 8; ++j2) ca[j2] = va[j2] - 1.0;
                    #pragma unroll
                    for (int g2 = 0; g2 < TPB; g2 += 16) {
                        #pragma unroll
                        for (int j2 = 0; j2 < 8; ++j2) vb8[j2] = Is[p][g2 + 8 + j2][c];
                        #pragma unroll
                        for (int j2 = 0; j2 < 8; ++j2) cb2[j2] = vb8[j2] - 1.0;
                        #pragma unroll
                        for (int j2 = 0; j2 < 8; ++j2) {
                            double m1 = fma(0.95, mem, va[j2]);
                            double m2 = fma(0.95, mem, ca[j2]);
                            mem = r ? m2 : m1;
                            r = mem > 1.0;
                            const int s = g2 + j2;
                            if (s < 64) bits0 |= (unsigned long long)(r ? 1 : 0) << s;
                            else        bits1 |= (unsigned long long)(r ? 1 : 0) << (s - 64);
                        }
                        if (g2 + 16 < TPB) {
                            #pragma unroll
                            for (int j2 = 0; j2 < 8; ++j2) va[j2] = Is[p][g2 + 16 + j2][c];
                            #pragma unroll
                            for (int j2 = 0; j2 < 8; ++j2) ca[j2] = va[j2] - 1.0;
                        }
                        #pragma unroll
                        for (int j2 = 0; j2 < 8; ++j2) {
                            double m1 = fma(0.95, mem, vb8[j2]);
                            double m2 = fma(0.95, mem, cb2[j2]);
                            mem = r ? m2 : m1;
                            r = mem > 1.0;
                            const int s = g2 + 8 + j2;
                            if (s < 64) bits0 |= (unsigned long long)(r ? 1 : 0) << s;
                            else        bits1 |= (unsigned long long)(r ? 1 : 0) << (s - 64);
                        }
                    }
                    bitsb[p][c][0] = bits0;
                    bitsb[p][c][1] = bits1;
                }
                __builtin_amdgcn_s_setprio(0);
            }
        }
        bar_lds();
    };

    // ping-pong register sets (statically indexed — rule #20)
    float  rA[2][16], rB[2][16];
    double kA[2][7],  kB[2][7];

    // prologue: issue tiles 0 (set A) and 1 (set B)
    if (tid >= 64) {
        issue(0, rA, kA);
        issue(1, rB, kB);
    }

    // 18 phases, unrolled by 2 so reg-set parity is static
    for (int kk = 0; kk < NT + 2; kk += 2) {
        phase(kk,     rA, kA);
        phase(kk + 1, rB, kB);
    }
}

// ---------------------------------------------------------------------------
extern "C" void kernel_launch(void* const* d_in, const int* in_sizes, int n_in,
                              void* d_out, int out_size, void* d_ws, size_t ws_size,
                              hipStream_t stream)
{
    const float* x  = (const float*)d_in[0];   // (32,1,224,2048) f32
    const float* lw = (const float*)d_in[1];   // (1,224) f32
    float* out = (float*)d_out;                // (32,1,224,2048) f32

    double* kernG = (double*)d_ws;             // 65536 * 7 * 8 = 3,670,016 B

    kw<<<dim3(TTT / 64, BB), 256, 0, stream>>>(x, lw, kernG);
    kf<<<dim3(NCG, BB), 512, 0, stream>>>(x, kernG, out);
}